// Round 1
// baseline (299.348 us; speedup 1.0000x reference)
//
#include <hip/hip_runtime.h>
#include <cmath>

#define NNODES 4096
#define FDIM 512
#define DH 64
#define CAP 128

// ---------------------------------------------------------------------------
// Kernel 1: scan dense adjacency rows, compact nonzero column indices.
// One block per row; 64 MB total coalesced float4 read (the HBM floor).
// Order within a row is arbitrary (atomic slot assignment) — sums are
// order-independent within fp32 rounding, far inside the 1.56e-2 threshold.
// ---------------------------------------------------------------------------
__global__ __launch_bounds__(256) void build_nbr_kernel(
    const float* __restrict__ adj, int* __restrict__ nbr, int* __restrict__ deg)
{
    int row = blockIdx.x;
    __shared__ int cnt;
    if (threadIdx.x == 0) cnt = 0;
    __syncthreads();
    const float4* arow = reinterpret_cast<const float4*>(adj + (size_t)row * NNODES);
    int* nrow = nbr + (size_t)row * CAP;
    for (int c4 = threadIdx.x; c4 < NNODES / 4; c4 += 256) {
        float4 v = arow[c4];
        int base = c4 * 4;
        if (v.x != 0.f) { int p = atomicAdd(&cnt, 1); if (p < CAP) nrow[p] = base + 0; }
        if (v.y != 0.f) { int p = atomicAdd(&cnt, 1); if (p < CAP) nrow[p] = base + 1; }
        if (v.z != 0.f) { int p = atomicAdd(&cnt, 1); if (p < CAP) nrow[p] = base + 2; }
        if (v.w != 0.f) { int p = atomicAdd(&cnt, 1); if (p < CAP) nrow[p] = base + 3; }
    }
    __syncthreads();
    if (threadIdx.x == 0) deg[row] = cnt < CAP ? cnt : CAP;
}

// ---------------------------------------------------------------------------
// Kernel 2: x = h @ W   ([4096,512] @ [512,64] -> [4096,64], fp32)
// lane = output column (coalesced W reads); each thread owns 4 rows
// (h loads are wave-uniform broadcasts, float4-vectorized over K).
// ---------------------------------------------------------------------------
__global__ __launch_bounds__(256) void feat_mm_kernel(
    const float* __restrict__ h, const float* __restrict__ W, float* __restrict__ x)
{
    const int tx = threadIdx.x;                        // 0..63: output col
    const int r0 = blockIdx.x * 16 + threadIdx.y * 4;  // 4 rows per thread
    const float* h0 = h + (size_t)r0 * FDIM;
    float acc0 = 0.f, acc1 = 0.f, acc2 = 0.f, acc3 = 0.f;
    for (int k = 0; k < FDIM; k += 4) {
        float w0 = W[(k + 0) * DH + tx];
        float w1 = W[(k + 1) * DH + tx];
        float w2 = W[(k + 2) * DH + tx];
        float w3 = W[(k + 3) * DH + tx];
        float4 a0 = *reinterpret_cast<const float4*>(h0 + 0 * FDIM + k);
        float4 a1 = *reinterpret_cast<const float4*>(h0 + 1 * FDIM + k);
        float4 a2 = *reinterpret_cast<const float4*>(h0 + 2 * FDIM + k);
        float4 a3 = *reinterpret_cast<const float4*>(h0 + 3 * FDIM + k);
        acc0 = fmaf(a0.x, w0, fmaf(a0.y, w1, fmaf(a0.z, w2, fmaf(a0.w, w3, acc0))));
        acc1 = fmaf(a1.x, w0, fmaf(a1.y, w1, fmaf(a1.z, w2, fmaf(a1.w, w3, acc1))));
        acc2 = fmaf(a2.x, w0, fmaf(a2.y, w1, fmaf(a2.z, w2, fmaf(a2.w, w3, acc2))));
        acc3 = fmaf(a3.x, w0, fmaf(a3.y, w1, fmaf(a3.z, w2, fmaf(a3.w, w3, acc3))));
    }
    x[(size_t)(r0 + 0) * DH + tx] = acc0;
    x[(size_t)(r0 + 1) * DH + tx] = acc1;
    x[(size_t)(r0 + 2) * DH + tx] = acc2;
    x[(size_t)(r0 + 3) * DH + tx] = acc3;
}

// ---------------------------------------------------------------------------
// Kernel 3: el = x@al, er = x@ar  ([4096,64]@[64,H] -> [4096,H])
// One wave per node, lane = feature dim, butterfly shuffle reduction.
// ---------------------------------------------------------------------------
template <int H>
__global__ __launch_bounds__(256) void attn_proj_kernel(
    const float* __restrict__ x, const float* __restrict__ al, const float* __restrict__ ar,
    float* __restrict__ el, float* __restrict__ er)
{
    int node = blockIdx.x * 4 + threadIdx.y;
    int lane = threadIdx.x;
    float xv = x[(size_t)node * DH + lane];
#pragma unroll
    for (int h = 0; h < H; h++) {
        float vl = xv * al[lane * H + h];
        float vr = xv * ar[lane * H + h];
#pragma unroll
        for (int off = 32; off >= 1; off >>= 1) {
            vl += __shfl_xor(vl, off, 64);
            vr += __shfl_xor(vr, off, 64);
        }
        if (lane == 0) {
            el[node * H + h] = vl;
            er[node * H + h] = vr;
        }
    }
}

// ---------------------------------------------------------------------------
// Kernel 4: sparse GAT aggregate.
// One wave per node i, lane = output dim d. For each neighbor j:
//   w = exp(leaky_relu(el[i,h] + er[j,h])); acc[h] += w*x[j,d]; den[h] += w
// out[i, h*64+d] = elu(acc/max(den,1e-12) + b[d])   (elu only if ACT)
// x (1 MB) / er (128 KB) / nbr (2 MB) are L2-resident -> scattered but cached.
// ---------------------------------------------------------------------------
template <int H, bool ACT>
__global__ __launch_bounds__(256) void aggregate_kernel(
    const float* __restrict__ x, const float* __restrict__ el, const float* __restrict__ er,
    const int* __restrict__ nbr, const int* __restrict__ deg, const float* __restrict__ bias,
    float* __restrict__ out)
{
    int node = blockIdx.x * 4 + threadIdx.y;
    int lane = threadIdx.x;
    float eli[H], acc[H], den[H];
#pragma unroll
    for (int h = 0; h < H; h++) {
        eli[h] = el[node * H + h];
        acc[h] = 0.f;
        den[h] = 0.f;
    }
    int dg = deg[node];
    const int* nb = nbr + (size_t)node * CAP;
    for (int k = 0; k < dg; k++) {
        int j = nb[k];
        float xv = x[(size_t)j * DH + lane];
        float erj[H];
#pragma unroll
        for (int h = 0; h < H; h++) erj[h] = er[j * H + h];
#pragma unroll
        for (int h = 0; h < H; h++) {
            float s = eli[h] + erj[h];
            s = s > 0.f ? s : 0.2f * s;          // leaky_relu(0.2)
            float w = __expf(s);
            acc[h] = fmaf(w, xv, acc[h]);
            den[h] += w;
        }
    }
    float bv = bias[lane];
#pragma unroll
    for (int h = 0; h < H; h++) {
        float o = acc[h] / fmaxf(den[h], 1e-12f) + bv;
        if (ACT) o = o > 0.f ? o : expm1f(o);    // elu(alpha=1)
        out[(size_t)node * (H * DH) + h * DH + lane] = o;
    }
}

// ---------------------------------------------------------------------------
extern "C" void kernel_launch(void* const* d_in, const int* in_sizes, int n_in,
                              void* d_out, int out_size, void* d_ws, size_t ws_size,
                              hipStream_t stream)
{
    const float* adj  = (const float*)d_in[0];
    const float* feat = (const float*)d_in[1];
    const float* W0   = (const float*)d_in[2];
    const float* al0  = (const float*)d_in[3];
    const float* ar0  = (const float*)d_in[4];
    const float* b0   = (const float*)d_in[5];
    const float* W1   = (const float*)d_in[6];
    const float* al1  = (const float*)d_in[7];
    const float* ar1  = (const float*)d_in[8];
    const float* b1   = (const float*)d_in[9];
    const float* W2   = (const float*)d_in[10];
    const float* al2  = (const float*)d_in[11];
    const float* ar2  = (const float*)d_in[12];
    const float* b2   = (const float*)d_in[13];
    float* out = (float*)d_out;

    // workspace layout (all 16B-aligned): ~11.3 MB total
    char* ws = (char*)d_ws;
    int*   nbr  = (int*)ws;   ws += (size_t)NNODES * CAP * sizeof(int);   // 2 MB
    int*   deg  = (int*)ws;   ws += (size_t)NNODES * sizeof(int);         // 16 KB
    float* x    = (float*)ws; ws += (size_t)NNODES * DH * sizeof(float);  // 1 MB
    float* el   = (float*)ws; ws += (size_t)NNODES * 8 * sizeof(float);   // 128 KB
    float* er   = (float*)ws; ws += (size_t)NNODES * 8 * sizeof(float);   // 128 KB
    float* hbuf = (float*)ws; ws += (size_t)NNODES * FDIM * sizeof(float);// 8 MB

    dim3 wb(64, 4);  // one wave per node, 4 waves/block

    // edge extraction (single 64 MB adj pass)
    build_nbr_kernel<<<NNODES, 256, 0, stream>>>(adj, nbr, deg);

    // layer 0: feats(512) -> 8 heads x 64, elu
    feat_mm_kernel<<<NNODES / 16, wb, 0, stream>>>(feat, W0, x);
    attn_proj_kernel<8><<<NNODES / 4, wb, 0, stream>>>(x, al0, ar0, el, er);
    aggregate_kernel<8, true><<<NNODES / 4, wb, 0, stream>>>(x, el, er, nbr, deg, b0, hbuf);

    // layer 1: 512 -> 8 heads x 64, elu
    feat_mm_kernel<<<NNODES / 16, wb, 0, stream>>>(hbuf, W1, x);
    attn_proj_kernel<8><<<NNODES / 4, wb, 0, stream>>>(x, al1, ar1, el, er);
    aggregate_kernel<8, true><<<NNODES / 4, wb, 0, stream>>>(x, el, er, nbr, deg, b1, hbuf);

    // layer 2: 512 -> 1 head x 64, no activation, to d_out
    feat_mm_kernel<<<NNODES / 16, wb, 0, stream>>>(hbuf, W2, x);
    attn_proj_kernel<1><<<NNODES / 4, wb, 0, stream>>>(x, al2, ar2, el, er);
    aggregate_kernel<1, false><<<NNODES / 4, wb, 0, stream>>>(x, el, er, nbr, deg, b2, out);
}

// Round 2
// 268.016 us; speedup vs baseline: 1.1169x; 1.1169x over previous
//
#include <hip/hip_runtime.h>
#include <cmath>

#define NNODES 4096
#define FDIM 512
#define DH 64
#define CAP 128

// ---------------------------------------------------------------------------
// Kernel 1: scan dense adjacency rows, compact nonzero column indices.
// One block per row; 64 MB coalesced float4 read (the HBM floor, ~11 us).
// ---------------------------------------------------------------------------
__global__ __launch_bounds__(256) void build_nbr_kernel(
    const float* __restrict__ adj, int* __restrict__ nbr, int* __restrict__ deg)
{
    int row = blockIdx.x;
    __shared__ int cnt;
    if (threadIdx.x == 0) cnt = 0;
    __syncthreads();
    const float4* arow = reinterpret_cast<const float4*>(adj + (size_t)row * NNODES);
    int* nrow = nbr + (size_t)row * CAP;
    for (int c4 = threadIdx.x; c4 < NNODES / 4; c4 += 256) {
        float4 v = arow[c4];
        int base = c4 * 4;
        if (v.x != 0.f) { int p = atomicAdd(&cnt, 1); if (p < CAP) nrow[p] = base + 0; }
        if (v.y != 0.f) { int p = atomicAdd(&cnt, 1); if (p < CAP) nrow[p] = base + 1; }
        if (v.z != 0.f) { int p = atomicAdd(&cnt, 1); if (p < CAP) nrow[p] = base + 2; }
        if (v.w != 0.f) { int p = atomicAdd(&cnt, 1); if (p < CAP) nrow[p] = base + 3; }
    }
    __syncthreads();
    if (threadIdx.x == 0) deg[row] = cnt < CAP ? cnt : CAP;
}

// ---------------------------------------------------------------------------
// Kernel 2 (fused mm + proj): x = h@W, el = x@al, er = x@ar.
// Block = 4 rows, 4 waves; wave w computes the K-quarter [w*128, w*128+128)
// for all 4 rows (lane = output col; W loads coalesced, h loads broadcast).
// Partials reduced through LDS; then wave w owns row w: writes x-row and
// does the 8-head el/er shuffle reductions.
// Grid = 1024 blocks -> 4 blocks/CU, 4 waves/SIMD (vs 1/SIMD before).
// ---------------------------------------------------------------------------
template <int H>
__global__ __launch_bounds__(256, 4) void mm_proj_kernel(
    const float* __restrict__ h, const float* __restrict__ W,
    const float* __restrict__ al, const float* __restrict__ ar,
    float* __restrict__ x, float* __restrict__ el, float* __restrict__ er)
{
    __shared__ float part[4][4][DH];   // [wave][row][col] = 4 KB
    const int lane = threadIdx.x;      // output col
    const int wv = threadIdx.y;        // wave id = K-quarter id
    const int r0 = blockIdx.x * 4;

    float acc[4] = {0.f, 0.f, 0.f, 0.f};
    const int k0 = wv * (FDIM / 4);
    for (int k = k0; k < k0 + FDIM / 4; k += 4) {
        float w0 = W[(k + 0) * DH + lane];
        float w1 = W[(k + 1) * DH + lane];
        float w2 = W[(k + 2) * DH + lane];
        float w3 = W[(k + 3) * DH + lane];
#pragma unroll
        for (int r = 0; r < 4; r++) {
            float4 a = *reinterpret_cast<const float4*>(h + (size_t)(r0 + r) * FDIM + k);
            acc[r] = fmaf(a.x, w0, fmaf(a.y, w1, fmaf(a.z, w2, fmaf(a.w, w3, acc[r]))));
        }
    }
#pragma unroll
    for (int r = 0; r < 4; r++) part[wv][r][lane] = acc[r];
    __syncthreads();

    // wave wv finalizes row wv
    float xv = part[0][wv][lane] + part[1][wv][lane] + part[2][wv][lane] + part[3][wv][lane];
    const int node = r0 + wv;
    x[(size_t)node * DH + lane] = xv;
#pragma unroll
    for (int hh = 0; hh < H; hh++) {
        float vl = xv * al[lane * H + hh];
        float vr = xv * ar[lane * H + hh];
#pragma unroll
        for (int off = 32; off >= 1; off >>= 1) {
            vl += __shfl_xor(vl, off, 64);
            vr += __shfl_xor(vr, off, 64);
        }
        if (lane == 0) {
            el[node * H + hh] = vl;
            er[node * H + hh] = vr;
        }
    }
}

// ---------------------------------------------------------------------------
// Kernel 3: sparse GAT aggregate. One wave per (node, head-group); lane =
// output dim. GPN groups/node (2 for H=8) doubles wave count to 8 waves/SIMD;
// neighbor loop unrolled x2 so two scattered x/er loads are in flight.
// x (1 MB) / er (128 KB) / nbr (2 MB) are L2-resident.
// ---------------------------------------------------------------------------
template <int H, int GPN, bool ACT>
__global__ __launch_bounds__(256) void aggregate_kernel(
    const float* __restrict__ x, const float* __restrict__ el, const float* __restrict__ er,
    const int* __restrict__ nbr, const int* __restrict__ deg, const float* __restrict__ bias,
    float* __restrict__ out)
{
    constexpr int HPG = H / GPN;       // heads per group
    const int widx = blockIdx.x * 4 + threadIdx.y;
    const int node = widx / GPN;
    const int h0 = (widx % GPN) * HPG;
    const int lane = threadIdx.x;

    float eli[HPG], acc[HPG], den[HPG];
#pragma unroll
    for (int hh = 0; hh < HPG; hh++) {
        eli[hh] = el[node * H + h0 + hh];
        acc[hh] = 0.f;
        den[hh] = 0.f;
    }
    const int dg = deg[node];
    const int* nb = nbr + (size_t)node * CAP;

    int k = 0;
    for (; k + 2 <= dg; k += 2) {
        int j0 = nb[k], j1 = nb[k + 1];
        float xv0 = x[(size_t)j0 * DH + lane];
        float xv1 = x[(size_t)j1 * DH + lane];
        float e0[HPG], e1[HPG];
#pragma unroll
        for (int hh = 0; hh < HPG; hh++) {
            e0[hh] = er[j0 * H + h0 + hh];
            e1[hh] = er[j1 * H + h0 + hh];
        }
#pragma unroll
        for (int hh = 0; hh < HPG; hh++) {
            float s0 = eli[hh] + e0[hh];
            float s1 = eli[hh] + e1[hh];
            s0 = s0 > 0.f ? s0 : 0.2f * s0;
            s1 = s1 > 0.f ? s1 : 0.2f * s1;
            float w0 = __expf(s0), w1 = __expf(s1);
            acc[hh] = fmaf(w0, xv0, acc[hh]);
            acc[hh] = fmaf(w1, xv1, acc[hh]);
            den[hh] += w0 + w1;
        }
    }
    if (k < dg) {
        int j = nb[k];
        float xv = x[(size_t)j * DH + lane];
#pragma unroll
        for (int hh = 0; hh < HPG; hh++) {
            float s = eli[hh] + er[j * H + h0 + hh];
            s = s > 0.f ? s : 0.2f * s;
            float w = __expf(s);
            acc[hh] = fmaf(w, xv, acc[hh]);
            den[hh] += w;
        }
    }

    float bv = bias[lane];
#pragma unroll
    for (int hh = 0; hh < HPG; hh++) {
        float o = acc[hh] / fmaxf(den[hh], 1e-12f) + bv;
        if (ACT) o = o > 0.f ? o : __expf(o) - 1.f;   // elu(alpha=1)
        out[(size_t)node * (H * DH) + (h0 + hh) * DH + lane] = o;
    }
}

// ---------------------------------------------------------------------------
extern "C" void kernel_launch(void* const* d_in, const int* in_sizes, int n_in,
                              void* d_out, int out_size, void* d_ws, size_t ws_size,
                              hipStream_t stream)
{
    const float* adj  = (const float*)d_in[0];
    const float* feat = (const float*)d_in[1];
    const float* W0   = (const float*)d_in[2];
    const float* al0  = (const float*)d_in[3];
    const float* ar0  = (const float*)d_in[4];
    const float* b0   = (const float*)d_in[5];
    const float* W1   = (const float*)d_in[6];
    const float* al1  = (const float*)d_in[7];
    const float* ar1  = (const float*)d_in[8];
    const float* b1   = (const float*)d_in[9];
    const float* W2   = (const float*)d_in[10];
    const float* al2  = (const float*)d_in[11];
    const float* ar2  = (const float*)d_in[12];
    const float* b2   = (const float*)d_in[13];
    float* out = (float*)d_out;

    // workspace layout (16B-aligned), ~11.3 MB total
    char* ws = (char*)d_ws;
    int*   nbr  = (int*)ws;   ws += (size_t)NNODES * CAP * sizeof(int);   // 2 MB
    int*   deg  = (int*)ws;   ws += (size_t)NNODES * sizeof(int);         // 16 KB
    float* x    = (float*)ws; ws += (size_t)NNODES * DH * sizeof(float);  // 1 MB
    float* el   = (float*)ws; ws += (size_t)NNODES * 8 * sizeof(float);   // 128 KB
    float* er   = (float*)ws; ws += (size_t)NNODES * 8 * sizeof(float);   // 128 KB
    float* hbuf = (float*)ws; ws += (size_t)NNODES * FDIM * sizeof(float);// 8 MB

    dim3 wb(64, 4);

    build_nbr_kernel<<<NNODES, 256, 0, stream>>>(adj, nbr, deg);

    // layer 0
    mm_proj_kernel<8><<<NNODES / 4, wb, 0, stream>>>(feat, W0, al0, ar0, x, el, er);
    aggregate_kernel<8, 2, true><<<NNODES * 2 / 4, wb, 0, stream>>>(x, el, er, nbr, deg, b0, hbuf);
    // layer 1
    mm_proj_kernel<8><<<NNODES / 4, wb, 0, stream>>>(hbuf, W1, al1, ar1, x, el, er);
    aggregate_kernel<8, 2, true><<<NNODES * 2 / 4, wb, 0, stream>>>(x, el, er, nbr, deg, b1, hbuf);
    // layer 2 (1 head, no activation) -> d_out
    mm_proj_kernel<1><<<NNODES / 4, wb, 0, stream>>>(hbuf, W2, al2, ar2, x, el, er);
    aggregate_kernel<1, 1, false><<<NNODES / 4, wb, 0, stream>>>(x, el, er, nbr, deg, b2, out);
}